// Round 10
// baseline (4797.247 us; speedup 1.0000x reference)
//
#include <hip/hip_runtime.h>

typedef _Float16 f16;
typedef f16  f16x8 __attribute__((ext_vector_type(8)));
typedef float f32x4 __attribute__((ext_vector_type(4)));
typedef unsigned int u32;
typedef unsigned long long u64;
typedef u32 u32x4 __attribute__((ext_vector_type(4)));

// Problem dims
#define NB   32
#define NT   512
#define NM   6
#define NH   512
#define NH3  1536
#define PADTOK 1
#define LO_SCALE 4096.0f
#define LO_INV   (1.0f/4096.0f)

// ws layout (bytes):
//  A2    [16448][1024] f16 : 33,685,504 @ 0   (rows 0..16383 outs b*T+t, 16384..16415 hidden, 16416+ zeroed)
//  Ahi   [16384][512]  f16 : 16 MB @ 0          (ALIASES A2 rows 0..8191 -- dead before k_recur writes A2)
//  Alo   [16384][512]  f16 : 16 MB @ 16777216
//  xs_f  [512][32][1536] f16 (t-major) @ 33685504
//  xs_b  same @ 84017152
//  xhlo_f [512][32][512] f16 @ 134348800
//  xhlo_b same @ 151126016
//  hb32  [2 dir][2 par][32][512] u32 @ 167903232 (262,144)
//        element: hi_f16 | ((lo_f16 & 0xFFFC | tag2) << 16); tag = step & 3 (R7 format).
//        Planes pre-invalidated each launch by k_embed: plane0 tag=1, plane1 tag=0.
//  flags [2 dir][32 slice][544 step-slots] u32 @ 168165376 (139,264)
//        write-once 0->1 per launch, slice-major (R9 layout). Zeroed by k_embed.
#define FLAGS_OFF 168165376
#define SLOT_STRIDE 544
#define FLAGS_U32 (2 * 32 * SLOT_STRIDE)   // 34816
#define HB_U32 (2 * 2 * NB * NH)           // 65536

// ---------------- embedding + flag zero + hb invalidation ----------------
__global__ __launch_bounds__(128) void k_embed(const int* __restrict__ seqs,
                                               const float* __restrict__ emb,
                                               f16* __restrict__ Ahi,
                                               f16* __restrict__ Alo,
                                               f16* __restrict__ A2,
                                               u32* __restrict__ flags,
                                               u32* __restrict__ hb32) {
  int row = blockIdx.x;           // b*NT + t
  int tid = threadIdx.x;          // 128
  if (row < 32) {                 // zero A2 pad rows 16416..16447
    for (int c2 = tid; c2 < 1024; c2 += 128)
      A2[(size_t)(16416 + row) * 1024 + c2] = (f16)0.f;
  }
  if (row < 64) {                 // zero flag slots (every launch, graph-replay safe)
    for (int j = row * 128 + tid; j < FLAGS_U32; j += 64 * 128)
      flags[j] = 0u;
  }
  if (row >= 64 && row < 128) {   // invalidate h tag planes (cross-replay ABA guard, R7-proven)
    for (int j = (row - 64) * 128 + tid; j < HB_U32; j += 64 * 128) {
      u32 par = (j >> 14) & 1;    // [d][par][32][512]: par bit at index bit 14
      hb32[j] = par ? 0x00000000u : 0x00010000u;   // tag invalid for that plane
    }
  }
  const int* tr = seqs + (size_t)row * NM;
  int c0 = tid * 4;
  float acc0 = 0.f, acc1 = 0.f, acc2 = 0.f, acc3 = 0.f;
  for (int m = 0; m < NM; m++) {
    int tk = tr[m];
    if (tk != PADTOK) {
      float4 ev = *(const float4*)(emb + (size_t)tk * NH + c0);
      acc0 += ev.x; acc1 += ev.y; acc2 += ev.z; acc3 += ev.w;
    }
  }
  float a[4] = {acc0, acc1, acc2, acc3};
  for (int j = 0; j < 4; j++) {
    float v = a[j];
    f16 h = (f16)v;
    float lo = (v - (float)h) * LO_SCALE;
    Ahi[(size_t)row * NH + c0 + j] = h;
    Alo[(size_t)row * NH + c0 + j] = (f16)lo;
  }
}

// ---------------- input GEMM: xs = emb @ kernel + b_in ----------------
__global__ __launch_bounds__(256) void k_gemm_in(const f16* __restrict__ Ahi,
                                                 const f16* __restrict__ Alo,
                                                 const float* __restrict__ Bw,    // [512][1536]
                                                 const float* __restrict__ bias,  // b[0][1536]
                                                 f16* __restrict__ Cxs,           // [512][32][1536]
                                                 f16* __restrict__ Clo) {         // [512][32][512] xh-lo
  __shared__ f16 BsH[64][40];
  __shared__ f16 BsL[64][40];
  int bx = blockIdx.x, by = blockIdx.y;
  int tid = threadIdx.x;
  int w = tid >> 6, l = tid & 63;
  int row0 = bx * 64 + w * 16;
  int col0 = by * 64;
  int arow = row0 + (l & 15);
  int kg = (l >> 4) * 8;
  f32x4 acc[4], accs[4];
  for (int nt = 0; nt < 4; nt++) {
    float bv = bias[col0 + nt * 16 + (l & 15)];
    f32x4 t = {bv, bv, bv, bv};
    acc[nt] = t;
    f32x4 z = {0.f, 0.f, 0.f, 0.f};
    accs[nt] = z;
  }
  for (int kb = 0; kb < NH; kb += 32) {
    __syncthreads();
    for (int idx = tid; idx < 2048; idx += 256) {
      int n = idx & 63, kl = idx >> 6;
      float v = Bw[(size_t)(kb + kl) * NH3 + col0 + n];
      f16 h = (f16)v;
      BsH[n][kl] = h;
      BsL[n][kl] = (f16)((v - (float)h) * LO_SCALE);
    }
    __syncthreads();
    f16x8 ah = *(const f16x8*)(Ahi + (size_t)arow * NH + kb + kg);
    f16x8 al = *(const f16x8*)(Alo + (size_t)arow * NH + kb + kg);
    for (int nt = 0; nt < 4; nt++) {
      f16x8 bh = *(const f16x8*)(&BsH[nt * 16 + (l & 15)][kg]);
      f16x8 bl = *(const f16x8*)(&BsL[nt * 16 + (l & 15)][kg]);
      acc[nt]  = __builtin_amdgcn_mfma_f32_16x16x32_f16(ah, bh, acc[nt], 0, 0, 0);
      accs[nt] = __builtin_amdgcn_mfma_f32_16x16x32_f16(al, bh, accs[nt], 0, 0, 0);
      accs[nt] = __builtin_amdgcn_mfma_f32_16x16x32_f16(ah, bl, accs[nt], 0, 0, 0);
    }
  }
  for (int nt = 0; nt < 4; nt++)
    for (int r = 0; r < 4; r++) {
      int grow = row0 + (l >> 4) * 4 + r;          // = b*NT + t
      int gcol = col0 + nt * 16 + (l & 15);
      int pr = (grow & (NT - 1)) * 32 + (grow >> 9); // t*32 + b
      float v = acc[nt][r] + accs[nt][r] * LO_INV;
      f16 h = (f16)v;
      Cxs[(size_t)pr * NH3 + gcol] = h;
      if (gcol >= 2 * NH)
        Clo[(size_t)pr * NH + (gcol - 2 * NH)] = (f16)(v - (float)h);
    }
}

// ---------------- recurrence (plain launch; 64 wgs co-resident, 1/CU) ----------------
// 64 wgs: dir = wg>>5, slice = wg&31. rk slice hi/lo in LDS (96KB).
// Exchange: flags gate detection (write-once, R9); 2-bit step tags in the data
// validate completion (R7). NO producer store-ack vmcnt -- saves one fabric RTT
// per step; stores that race past the flag are caught by tags and re-loaded.
__global__ __launch_bounds__(128) void k_recur(const f16* __restrict__ xs_f,
                                               const f16* __restrict__ xs_b,
                                               const f16* __restrict__ xhlo_f,
                                               const f16* __restrict__ xhlo_b,
                                               const float* __restrict__ rk_f,
                                               const float* __restrict__ rk_b,
                                               const float* __restrict__ b_f,
                                               const float* __restrict__ b_b,
                                               const int* __restrict__ lens,
                                               u32* __restrict__ hb32,
                                               f16* __restrict__ A2,
                                               u32* __restrict__ flags) {
  __shared__ f16 WsH[48 * 512];   // [n][k] XOR-swizzled, hi
  __shared__ f16 WsL[48 * 512];   // lo * 2^12
  int wg = blockIdx.x;
  int d = wg >> 5;
  int s = wg & 31;
  int u0 = s * 16;
  int tid = threadIdx.x;
  int w = tid >> 6, l = tid & 63;
  const f16*   xs = d ? xs_b : xs_f;
  const f16*   xlo = d ? xhlo_b : xhlo_f;
  const float* rk = d ? rk_b : rk_f;
  const float* bb = d ? b_b  : b_f;

  for (int idx = tid; idx < 48 * 512; idx += 128) {
    int k = idx / 48, n = idx % 48;
    int gcol = (n >> 4) * NH + u0 + (n & 15);
    float v = rk[(size_t)k * NH3 + gcol];
    f16 h = (f16)v;
    f16 lo = (f16)((v - (float)h) * LO_SCALE);
    int byte = (n * 1024 + k * 2) ^ ((n & 7) << 4);
    *(f16*)((char*)WsH + byte) = h;
    *(f16*)((char*)WsL + byte) = lo;
  }
  __syncthreads();   // Ws read-only hereafter

  int c = l & 15;
  float brz = bb[NH3 + 0 * NH + u0 + c];
  float brr = bb[NH3 + 1 * NH + u0 + c];
  float brh = bb[NH3 + 2 * NH + u0 + c];
  int mrow[4], lenv[4];
  float hstate[4];
  int wi_h[4];                     // u32 index within a plane: b*512 + u0 + c
  for (int r = 0; r < 4; r++) {
    int b = w * 16 + (l >> 4) * 4 + r;
    mrow[r] = b;
    lenv[r] = lens[b];
    hstate[r] = 0.f;
    wi_h[r] = b * NH + u0 + c;
  }
  const int PLANE = NB * NH;       // 16384 u32
  const int fbase = (d * 32 + s) * SLOT_STRIDE;
  // h0 = 0 (tag 0) into parity-0 plane; issue-order barrier; publish slot 0 (no ack)
  for (int r = 0; r < 4; r++)
    __hip_atomic_store(&hb32[(d * 2 + 0) * PLANE + wi_h[r]], 0u,
                       __ATOMIC_RELAXED, __HIP_MEMORY_SCOPE_AGENT);
  __syncthreads();
  if (tid == 0)
    __hip_atomic_store(&flags[fbase + 0], 1u,
                       __ATOMIC_RELAXED, __HIP_MEMORY_SCOPE_AGENT);

  int arow_b = w * 16 + (l & 15);
  int kg = (l >> 4) * 8;
  int cbase = c * 1024;
  int zc = (c & 7) << 4;
  const u64 TAGM = 0x0000000300000003ULL;

#pragma unroll 1
  for (int i = 0; i < NT; i++) {
    int t = d ? (NT - 1 - i) : i;
    int p = i & 1;
    const u32* hrow = hb32 + (size_t)(d * 2 + p) * PLANE + arow_b * NH;
    u32* wplane = hb32 + (size_t)(d * 2 + (p ^ 1)) * PLANE;
    const unsigned short* xrow = (const unsigned short*)(xs + (size_t)t * 32 * NH3);
    const unsigned short* xlorow = (const unsigned short*)(xlo + (size_t)t * 32 * NH);

    // 1) flags: every slice of this direction has ISSUED h_i (write-once slot i)
    if (tid < 32) {
      const u32* fp = flags + (d * 32 + tid) * SLOT_STRIDE + i;
      while (__hip_atomic_load(fp, __ATOMIC_RELAXED, __HIP_MEMORY_SCOPE_AGENT) == 0u)
        __builtin_amdgcn_s_sleep(1);
    }
    __syncthreads();

    // 2) bulk h load + tag validation; retries are rare (only stores that
    //    raced past their producer's flag).
    u32 want = (u32)i & 3u;
    u64 wp = (u64)want | ((u64)want << 32);
    u64 q[16][4];
    bool nd0 = true, nd1 = true, nd2 = true, nd3 = true;
    do {
#pragma unroll
      for (int g = 0; g < 4; g++) {
        bool nd = (g == 0) ? nd0 : (g == 1) ? nd1 : (g == 2) ? nd2 : nd3;
        if (nd) {
#pragma unroll
          for (int kk2 = 0; kk2 < 4; kk2++) {
            int kk = g * 4 + kk2;
            const u32* fb = hrow + kk * 32 + kg;
#pragma unroll
            for (int j = 0; j < 4; j++)
              q[kk][j] = __hip_atomic_load((const u64*)(fb + 2 * j),
                                           __ATOMIC_RELAXED, __HIP_MEMORY_SCOPE_AGENT);
          }
        }
      }
#pragma unroll
      for (int g = 0; g < 4; g++) {
        bool nd = (g == 0) ? nd0 : (g == 1) ? nd1 : (g == 2) ? nd2 : nd3;
        if (nd) {
          u64 acc = 0;
#pragma unroll
          for (int kk2 = 0; kk2 < 4; kk2++)
#pragma unroll
            for (int j = 0; j < 4; j++)
              acc |= ((q[g * 4 + kk2][j] >> 16) ^ wp) & TAGM;
          bool ok = __all(acc == 0ULL);
          if (g == 0) nd0 = !ok; else if (g == 1) nd1 = !ok;
          else if (g == 2) nd2 = !ok; else nd3 = !ok;
        }
      }
    } while (nd0 | nd1 | nd2 | nd3);

    // 3) xs as raw u16, issued after validation so its HBM latency hides
    //    under the MFMA loop (first use is in the epilogue)
    unsigned short rxz[4], rxr[4], rxh[4], rxl[4];
#pragma unroll
    for (int r = 0; r < 4; r++) {
      size_t o = (size_t)mrow[r] * NH3 + u0 + c;
      rxz[r] = xrow[o];
      rxr[r] = xrow[o + NH];
      rxh[r] = xrow[o + 2 * NH];
      rxl[r] = xlorow[(size_t)mrow[r] * NH + u0 + c];
    }

    f32x4 a0, a1, a2, s0, s1, s2;
#pragma unroll
    for (int r = 0; r < 4; r++) {
      a0[r] = 0.f; a1[r] = 0.f; a2[r] = 0.f;
      s0[r] = 0.f; s1[r] = 0.f; s2[r] = 0.f;
    }
#pragma unroll
    for (int kk = 0; kk < 16; kk++) {
      union { u32x4 w; f16x8 h; } A, L;
#pragma unroll
      for (int j = 0; j < 4; j++) {
        u32 w0 = (u32)q[kk][j];
        u32 w1 = (u32)(q[kk][j] >> 32);
        A.w[j] = __builtin_amdgcn_perm(w1, w0, 0x05040100u);               // hi halves
        L.w[j] = __builtin_amdgcn_perm(w1, w0, 0x07060302u) & 0xFFFCFFFCu; // lo, tags masked
      }
      int kb2 = (kk * 32 + kg) * 2;
      int off = (cbase + kb2) ^ zc;
      f16x8 b0h = *(const f16x8*)((const char*)WsH + off);
      f16x8 b1h = *(const f16x8*)((const char*)WsH + 16384 + off);
      f16x8 b2h = *(const f16x8*)((const char*)WsH + 32768 + off);
      f16x8 b0l = *(const f16x8*)((const char*)WsL + off);
      f16x8 b1l = *(const f16x8*)((const char*)WsL + 16384 + off);
      f16x8 b2l = *(const f16x8*)((const char*)WsL + 32768 + off);
      a0 = __builtin_amdgcn_mfma_f32_16x16x32_f16(A.h, b0h, a0, 0, 0, 0);
      s0 = __builtin_amdgcn_mfma_f32_16x16x32_f16(L.h, b0h, s0, 0, 0, 0);
      s0 = __builtin_amdgcn_mfma_f32_16x16x32_f16(A.h, b0l, s0, 0, 0, 0);
      a1 = __builtin_amdgcn_mfma_f32_16x16x32_f16(A.h, b1h, a1, 0, 0, 0);
      s1 = __builtin_amdgcn_mfma_f32_16x16x32_f16(L.h, b1h, s1, 0, 0, 0);
      s1 = __builtin_amdgcn_mfma_f32_16x16x32_f16(A.h, b1l, s1, 0, 0, 0);
      a2 = __builtin_amdgcn_mfma_f32_16x16x32_f16(A.h, b2h, a2, 0, 0, 0);
      s2 = __builtin_amdgcn_mfma_f32_16x16x32_f16(L.h, b2h, s2, 0, 0, 0);
      s2 = __builtin_amdgcn_mfma_f32_16x16x32_f16(A.h, b2l, s2, 0, 0, 0);
    }

    u32 wtag = (u32)(i + 1) & 3u;
#pragma unroll
    for (int r = 0; r < 4; r++) {
      union { unsigned short u; f16 f; } uz, ur, uh, ul;
      uz.u = rxz[r]; ur.u = rxr[r]; uh.u = rxh[r]; ul.u = rxl[r];
      float az = a0[r] + s0[r] * LO_INV + (float)uz.f + brz;
      float ar = a1[r] + s1[r] * LO_INV + (float)ur.f + brr;
      float ahg = a2[r] + s2[r] * LO_INV;
      float xh = (float)uh.f + (float)ul.f;
      float z  = 1.f / (1.f + __expf(-az));
      float rr = 1.f / (1.f + __expf(-ar));
      float hh = tanhf(xh + rr * (ahg + brh));
      float hn = z * hstate[r] + (1.f - z) * hh;
      bool msk = t < lenv[r];
      hn = msk ? hn : hstate[r];
      hstate[r] = hn;
      union { f16 f; unsigned short u; } chv, clv;
      chv.f = (f16)hn;
      float lof = (hn - (float)chv.f) * LO_SCALE;
      clv.f = (f16)lof;
      u32 packed = (u32)chv.u | ((((u32)clv.u & 0xFFFCu) | wtag) << 16);
      __hip_atomic_store(&wplane[wi_h[r]], packed,
                         __ATOMIC_RELAXED, __HIP_MEMORY_SCOPE_AGENT);
    }
    // issue-order barrier only (NO vmcnt store-ack); tags catch reordered stores
    __syncthreads();
    if (tid == 0)
      __hip_atomic_store(&flags[fbase + i + 1], 1u,
                         __ATOMIC_RELAXED, __HIP_MEMORY_SCOPE_AGENT);
#pragma unroll
    for (int r = 0; r < 4; r++)
      A2[((size_t)mrow[r] * NT + t) * 1024 + d * NH + u0 + c] = (f16)hstate[r];
  }
  for (int r = 0; r < 4; r++)
    A2[(size_t)(16384 + mrow[r]) * 1024 + d * NH + u0 + c] = (f16)hstate[r];
}

// ---------------- output projection ----------------
__global__ __launch_bounds__(256) void k_gemm_out(const f16* __restrict__ A2,   // [16448][1024]
                                                  const float* __restrict__ Wk, // [1024][512]
                                                  const float* __restrict__ Wb, // [512]
                                                  float* __restrict__ Out) {    // [16416][512]
  __shared__ f16 Bs[64][40];
  int bx = blockIdx.x, by = blockIdx.y;
  int tid = threadIdx.x;
  int w = tid >> 6, l = tid & 63;
  int row0 = bx * 64 + w * 16;
  int col0 = by * 64;
  int arow = row0 + (l & 15);
  int kg = (l >> 4) * 8;
  f32x4 acc[4];
  for (int nt = 0; nt < 4; nt++) {
    float bv = Wb[col0 + nt * 16 + (l & 15)];
    f32x4 t = {bv, bv, bv, bv};
    acc[nt] = t;
  }
  for (int kb = 0; kb < 1024; kb += 32) {
    __syncthreads();
    for (int idx = tid; idx < 2048; idx += 256) {
      int n = idx & 63, kl = idx >> 6;
      Bs[n][kl] = (f16)Wk[(size_t)(kb + kl) * NH + col0 + n];
    }
    __syncthreads();
    f16x8 av = *(const f16x8*)(A2 + (size_t)arow * 1024 + kb + kg);
    for (int nt = 0; nt < 4; nt++) {
      f16x8 bv = *(const f16x8*)(&Bs[nt * 16 + (l & 15)][kg]);
      acc[nt] = __builtin_amdgcn_mfma_f32_16x16x32_f16(av, bv, acc[nt], 0, 0, 0);
    }
  }
  for (int nt = 0; nt < 4; nt++)
    for (int r = 0; r < 4; r++) {
      int grow = row0 + (l >> 4) * 4 + r;
      if (grow < 16416)
        Out[(size_t)grow * NH + col0 + nt * 16 + (l & 15)] = acc[nt][r];
    }
}

extern "C" void kernel_launch(void* const* d_in, const int* in_sizes, int n_in,
                              void* d_out, int out_size, void* d_ws, size_t ws_size,
                              hipStream_t stream) {
  (void)in_sizes; (void)n_in; (void)out_size; (void)ws_size;
  const int*   seqs = (const int*)d_in[0];
  const int*   lens = (const int*)d_in[1];
  const float* emb  = (const float*)d_in[2];
  const float* k_f  = (const float*)d_in[3];
  const float* rk_f = (const float*)d_in[4];
  const float* b_f  = (const float*)d_in[5];
  const float* k_b  = (const float*)d_in[6];
  const float* rk_b = (const float*)d_in[7];
  const float* b_b  = (const float*)d_in[8];
  const float* Wk   = (const float*)d_in[9];
  const float* Wb   = (const float*)d_in[10];
  float* out = (float*)d_out;
  char* ws = (char*)d_ws;
  f16* A2     = (f16*)(ws + 0);
  f16* Ahi    = (f16*)(ws + 0);            // aliases A2; dead before A2 written
  f16* Alo    = (f16*)(ws + 16777216);
  f16* xs_f   = (f16*)(ws + 33685504);
  f16* xs_b   = (f16*)(ws + 84017152);
  f16* xhlo_f = (f16*)(ws + 134348800);
  f16* xhlo_b = (f16*)(ws + 151126016);
  u32* hb32   = (u32*)(ws + 167903232);
  u32* flags  = (u32*)(ws + FLAGS_OFF);

  hipLaunchKernelGGL(k_embed, dim3(16384), dim3(128), 0, stream, seqs, emb, Ahi, Alo, A2, flags, hb32);
  hipLaunchKernelGGL(k_gemm_in, dim3(256, 24), dim3(256), 0, stream, Ahi, Alo, k_f, b_f, xs_f, xhlo_f);
  hipLaunchKernelGGL(k_gemm_in, dim3(256, 24), dim3(256), 0, stream, Ahi, Alo, k_b, b_b, xs_b, xhlo_b);
  hipLaunchKernelGGL(k_recur, dim3(64), dim3(128), 0, stream,
                     xs_f, xs_b, xhlo_f, xhlo_b, rk_f, rk_b, b_f, b_b, lens, hb32, A2, flags);
  hipLaunchKernelGGL(k_gemm_out, dim3(257, 8), dim3(256), 0, stream, A2, Wk, Wb, out);
}

// Round 12
// 3773.989 us; speedup vs baseline: 1.2711x; 1.2711x over previous
//
#include <hip/hip_runtime.h>

typedef _Float16 f16;
typedef f16  f16x8 __attribute__((ext_vector_type(8)));
typedef float f32x4 __attribute__((ext_vector_type(4)));
typedef unsigned int u32;
typedef unsigned short u16;

// Problem dims
#define NB   32
#define NT   512
#define NM   6
#define NH   512
#define NH3  1536
#define PADTOK 1
#define LO_SCALE 4096.0f
#define LO_INV   (1.0f/4096.0f)

// ws layout (bytes):
//  A2    [16448][1024] f16 : 33,685,504 @ 0  (rows 0..16383 outs b*T+t, 16384..16415 hidden, 16416+ zeroed)
//  Ahi   [16384][512] f16 @ 0 (ALIASES A2 -- dead before k_recur writes A2); Alo @ 16,777,216
//        (k_embed's A2 pad-row writes start at byte 33,619,968 > Alo end 33,554,432 -- no overlap)
//  xs2_f [512 t][32 s][4 g][32 b][16 c] f16 @ 33,685,504 (67,108,864)   g: z,r,h,hlo -- 4KB/(t,s) blob
//  xs2_b same @ 100,794,368
//  hb    [2 dir][RING planes][32 s][32 b][16 c] f16 @ 167,903,232
//        WRITE-ONCE ring: plane p written exactly once (step p-1 producers), read exactly once
//        (step p consumers) per launch -> plain cached consumer loads are stale-proof.
//        Each 128B line belongs to ONE producer slice. RING=512 (33.5MB) if ws fits, else 64.
//  flags [2 d][32 slice][544] u32 after hb -- write-once 0->1, slice-major (R9-proven)
#define XS2F_OFF  33685504
#define XS2B_OFF  100794368
#define HB_OFF    167903232
#define SLOT_STRIDE 544
#define FLAGS_U32 (2 * 32 * SLOT_STRIDE)   // 34816
#define PLANE_E   16384                    // u16 elems per plane (32KB)

// producer-side device-scope store (L1/L2 bypass to MALL) -- R6/R9-proven class
__device__ __forceinline__ void coh_store_u16(u16* base, u32 voff, u32 val) {
  asm volatile("global_store_short %0, %1, %2 sc0 sc1"
               :: "v"(voff), "v"(val), "s"(base) : "memory");
}

// ---------------- embedding + flag zeroing ----------------
__global__ __launch_bounds__(128) void k_embed(const int* __restrict__ seqs,
                                               const float* __restrict__ emb,
                                               f16* __restrict__ Ahi,
                                               f16* __restrict__ Alo,
                                               f16* __restrict__ A2,
                                               u32* __restrict__ flags) {
  int row = blockIdx.x;           // b*NT + t
  int tid = threadIdx.x;          // 128
  if (row < 32) {                 // zero A2 pad rows 16416..16447
    for (int c2 = tid; c2 < 1024; c2 += 128)
      A2[(size_t)(16416 + row) * 1024 + c2] = (f16)0.f;
  }
  if (row < 64) {                 // zero flag slots (every launch, graph-replay safe)
    for (int j = row * 128 + tid; j < FLAGS_U32; j += 64 * 128)
      flags[j] = 0u;
  }
  const int* tr = seqs + (size_t)row * NM;
  int c0 = tid * 4;
  float acc0 = 0.f, acc1 = 0.f, acc2 = 0.f, acc3 = 0.f;
  for (int m = 0; m < NM; m++) {
    int tk = tr[m];
    if (tk != PADTOK) {
      float4 ev = *(const float4*)(emb + (size_t)tk * NH + c0);
      acc0 += ev.x; acc1 += ev.y; acc2 += ev.z; acc3 += ev.w;
    }
  }
  float a[4] = {acc0, acc1, acc2, acc3};
  for (int j = 0; j < 4; j++) {
    float v = a[j];
    f16 h = (f16)v;
    float lo = (v - (float)h) * LO_SCALE;
    Ahi[(size_t)row * NH + c0 + j] = h;
    Alo[(size_t)row * NH + c0 + j] = (f16)lo;
  }
}

// ---------------- input GEMM: xs2 = emb @ kernel + b_in, slice-blocked blob layout ----------------
__global__ __launch_bounds__(256) void k_gemm_in(const f16* __restrict__ Ahi,
                                                 const f16* __restrict__ Alo,
                                                 const float* __restrict__ Bw,    // [512][1536]
                                                 const float* __restrict__ bias,  // b[0][1536]
                                                 f16* __restrict__ xs2) {         // [512][32][4][32][16]
  __shared__ f16 BsH[64][40];
  __shared__ f16 BsL[64][40];
  int bx = blockIdx.x, by = blockIdx.y;
  int tid = threadIdx.x;
  int w = tid >> 6, l = tid & 63;
  int row0 = bx * 64 + w * 16;
  int col0 = by * 64;
  int arow = row0 + (l & 15);
  int kg = (l >> 4) * 8;
  f32x4 acc[4], accs[4];
  for (int nt = 0; nt < 4; nt++) {
    float bv = bias[col0 + nt * 16 + (l & 15)];
    f32x4 t = {bv, bv, bv, bv};
    acc[nt] = t;
    f32x4 z = {0.f, 0.f, 0.f, 0.f};
    accs[nt] = z;
  }
  for (int kb = 0; kb < NH; kb += 32) {
    __syncthreads();
    for (int idx = tid; idx < 2048; idx += 256) {
      int n = idx & 63, kl = idx >> 6;
      float v = Bw[(size_t)(kb + kl) * NH3 + col0 + n];
      f16 h = (f16)v;
      BsH[n][kl] = h;
      BsL[n][kl] = (f16)((v - (float)h) * LO_SCALE);
    }
    __syncthreads();
    f16x8 ah = *(const f16x8*)(Ahi + (size_t)arow * NH + kb + kg);
    f16x8 al = *(const f16x8*)(Alo + (size_t)arow * NH + kb + kg);
    for (int nt = 0; nt < 4; nt++) {
      f16x8 bh = *(const f16x8*)(&BsH[nt * 16 + (l & 15)][kg]);
      f16x8 bl = *(const f16x8*)(&BsL[nt * 16 + (l & 15)][kg]);
      acc[nt]  = __builtin_amdgcn_mfma_f32_16x16x32_f16(ah, bh, acc[nt], 0, 0, 0);
      accs[nt] = __builtin_amdgcn_mfma_f32_16x16x32_f16(al, bh, accs[nt], 0, 0, 0);
      accs[nt] = __builtin_amdgcn_mfma_f32_16x16x32_f16(ah, bl, accs[nt], 0, 0, 0);
    }
  }
  for (int nt = 0; nt < 4; nt++)
    for (int r = 0; r < 4; r++) {
      int grow = row0 + (l >> 4) * 4 + r;          // = b*NT + t
      int b = grow >> 9, t = grow & (NT - 1);
      int gcol = col0 + nt * 16 + (l & 15);
      int g = gcol >> 9, u = gcol & 511;
      int ss = u >> 4, cc = u & 15;
      float v = acc[nt][r] + accs[nt][r] * LO_INV;
      f16 h = (f16)v;
      size_t idx = (size_t)(t * 32 + ss) * 2048 + g * 512 + b * 16 + cc;
      xs2[idx] = h;
      if (g == 2)                                   // xh lo channel -> g=3 slot
        xs2[idx + 512] = (f16)(v - (float)h);
    }
}

// ---------------- recurrence (plain launch, 64 wgs, 1/CU) ----------------
// dir = wg>>5, slice = wg&31. rk slice hi/lo in LDS (96KB).
// Producers: sc0sc1 f16 stores + vmcnt ack + write-once flags (R9-proven protocol).
// Consumers: PLAIN CACHED f16x8 loads from write-once ring planes (stale-proof).
__global__ __launch_bounds__(128) void k_recur(const f16* __restrict__ xs2_f,
                                               const f16* __restrict__ xs2_b,
                                               const float* __restrict__ rk_f,
                                               const float* __restrict__ rk_b,
                                               const float* __restrict__ b_f,
                                               const float* __restrict__ b_b,
                                               const int* __restrict__ lens,
                                               u16* __restrict__ hb_f,
                                               u16* __restrict__ hb_b,
                                               f16* __restrict__ A2,
                                               u32* __restrict__ flags,
                                               int ring_mask) {
  __shared__ f16 WsH[48 * 512];   // [n][k] XOR-swizzled, hi
  __shared__ f16 WsL[48 * 512];   // lo * 2^12
  int wg = blockIdx.x;
  int d = wg >> 5;
  int s = wg & 31;
  int u0 = s * 16;
  int tid = threadIdx.x;
  int w = tid >> 6, l = tid & 63;
  const f16*   xs2 = d ? xs2_b : xs2_f;
  u16*         myhb = d ? hb_b : hb_f;
  const float* rk = d ? rk_b : rk_f;
  const float* bb = d ? b_b  : b_f;

  for (int idx = tid; idx < 48 * 512; idx += 128) {
    int k = idx / 48, n = idx % 48;
    int gcol = (n >> 4) * NH + u0 + (n & 15);
    float v = rk[(size_t)k * NH3 + gcol];
    f16 h = (f16)v;
    f16 lo = (f16)((v - (float)h) * LO_SCALE);
    int byte = (n * 1024 + k * 2) ^ ((n & 7) << 4);
    *(f16*)((char*)WsH + byte) = h;
    *(f16*)((char*)WsL + byte) = lo;
  }
  __syncthreads();   // Ws read-only hereafter

  int c = l & 15;
  float brz = bb[NH3 + 0 * NH + u0 + c];
  float brr = bb[NH3 + 1 * NH + u0 + c];
  float brh = bb[NH3 + 2 * NH + u0 + c];
  int mrow[4], lenv[4];
  float hstate[4];
  u32 vo_h[4];                     // byte offset within a plane: s*1024 + b*32 + c*2
  for (int r = 0; r < 4; r++) {
    int b = w * 16 + (l >> 4) * 4 + r;
    mrow[r] = b;
    lenv[r] = lens[b];
    hstate[r] = 0.f;
    vo_h[r] = (u32)(s * 1024 + b * 32 + c * 2);
  }
  const int fbase = (d * 32 + s) * SLOT_STRIDE;
  // h0 = 0 into plane 0; ack; publish slot 0
  for (int r = 0; r < 4; r++)
    coh_store_u16(myhb, vo_h[r], 0u);
  asm volatile("s_waitcnt vmcnt(0)" ::: "memory");
  __syncthreads();
  if (tid == 0)
    __hip_atomic_store(&flags[fbase + 0], 1u,
                       __ATOMIC_RELAXED, __HIP_MEMORY_SCOPE_AGENT);

  int arow_b = w * 16 + (l & 15);
  int kg = (l >> 4) * 8;
  int cbase = c * 1024;
  int zc = (c & 7) << 4;
  // per-lane base inside a plane for A-fragment reads:
  // cols C=kk*32+kg -> slice C>>4 (block 1KB), col C&15
  int hbase_lane = (kg >> 4) * 1024 + arow_b * 32 + (kg & 15) * 2;

#pragma unroll 1
  for (int i = 0; i < NT; i++) {
    int t = d ? (NT - 1 - i) : i;
    const u16* hplane = myhb + (size_t)(i & ring_mask) * PLANE_E;
    u16* wplane = myhb + (size_t)((i + 1) & ring_mask) * PLANE_E;

    // wait: every slice of this direction has published h_i (write-once slot i)
    if (tid < 32) {
      const u32* fp = flags + (d * 32 + tid) * SLOT_STRIDE + i;
      while (__hip_atomic_load(fp, __ATOMIC_RELAXED, __HIP_MEMORY_SCOPE_AGENT) == 0u)
        __builtin_amdgcn_s_sleep(1);
    }
    __syncthreads();   // also a compiler memory barrier: h loads cannot hoist above

    // xs blob: contiguous 4KB for (t, s); plain cached
    const u16* sl = (const u16*)(xs2 + (size_t)(t * 32 + s) * 2048);
    u16 rxz[4], rxr[4], rxh[4], rxl[4];
#pragma unroll
    for (int r = 0; r < 4; r++) {
      int bo = mrow[r] * 16 + c;
      rxz[r] = sl[bo];
      rxr[r] = sl[512 + bo];
      rxh[r] = sl[1024 + bo];
      rxl[r] = sl[1536 + bo];
    }

    f32x4 a0, a1, a2, s0, s1, s2;
#pragma unroll
    for (int r = 0; r < 4; r++) {
      a0[r] = 0.f; a1[r] = 0.f; a2[r] = 0.f;
      s0[r] = 0.f; s1[r] = 0.f; s2[r] = 0.f;
    }
#pragma unroll
    for (int kk = 0; kk < 16; kk++) {
      f16x8 ah = *(const f16x8*)((const char*)hplane + hbase_lane + kk * 2048);
      int kb2 = (kk * 32 + kg) * 2;
      int off = (cbase + kb2) ^ zc;
      f16x8 b0h = *(const f16x8*)((const char*)WsH + off);
      f16x8 b1h = *(const f16x8*)((const char*)WsH + 16384 + off);
      f16x8 b2h = *(const f16x8*)((const char*)WsH + 32768 + off);
      f16x8 b0l = *(const f16x8*)((const char*)WsL + off);
      f16x8 b1l = *(const f16x8*)((const char*)WsL + 16384 + off);
      f16x8 b2l = *(const f16x8*)((const char*)WsL + 32768 + off);
      a0 = __builtin_amdgcn_mfma_f32_16x16x32_f16(ah, b0h, a0, 0, 0, 0);
      s0 = __builtin_amdgcn_mfma_f32_16x16x32_f16(ah, b0l, s0, 0, 0, 0);
      a1 = __builtin_amdgcn_mfma_f32_16x16x32_f16(ah, b1h, a1, 0, 0, 0);
      s1 = __builtin_amdgcn_mfma_f32_16x16x32_f16(ah, b1l, s1, 0, 0, 0);
      a2 = __builtin_amdgcn_mfma_f32_16x16x32_f16(ah, b2h, a2, 0, 0, 0);
      s2 = __builtin_amdgcn_mfma_f32_16x16x32_f16(ah, b2l, s2, 0, 0, 0);
    }

#pragma unroll
    for (int r = 0; r < 4; r++) {
      union { u16 u; f16 f; } uz, ur, uh, ul;
      uz.u = rxz[r]; ur.u = rxr[r]; uh.u = rxh[r]; ul.u = rxl[r];
      float az = a0[r] + s0[r] * LO_INV + (float)uz.f + brz;
      float ar = a1[r] + s1[r] * LO_INV + (float)ur.f + brr;
      float ahg = a2[r] + s2[r] * LO_INV;
      float xh = (float)uh.f + (float)ul.f;
      float z  = 1.f / (1.f + __expf(-az));
      float rr = 1.f / (1.f + __expf(-ar));
      float hh = tanhf(xh + rr * (ahg + brh));
      float hn = z * hstate[r] + (1.f - z) * hh;
      bool msk = t < lenv[r];
      hn = msk ? hn : hstate[r];
      hstate[r] = hn;
      union { f16 f; u16 u; } chv;
      chv.f = (f16)hn;
      coh_store_u16(wplane, vo_h[r], (u32)chv.u);
    }
    // ack h stores at device scope, then publish slot i+1; A2 off the critical path
    asm volatile("s_waitcnt vmcnt(0)" ::: "memory");
    __syncthreads();
    if (tid == 0)
      __hip_atomic_store(&flags[fbase + i + 1], 1u,
                         __ATOMIC_RELAXED, __HIP_MEMORY_SCOPE_AGENT);
#pragma unroll
    for (int r = 0; r < 4; r++)
      A2[((size_t)mrow[r] * NT + t) * 1024 + d * NH + u0 + c] = (f16)hstate[r];
  }
  for (int r = 0; r < 4; r++)
    A2[(size_t)(16384 + mrow[r]) * 1024 + d * NH + u0 + c] = (f16)hstate[r];
}

// ---------------- output projection ----------------
__global__ __launch_bounds__(256) void k_gemm_out(const f16* __restrict__ A2,   // [16448][1024]
                                                  const float* __restrict__ Wk, // [1024][512]
                                                  const float* __restrict__ Wb, // [512]
                                                  float* __restrict__ Out) {    // [16416][512]
  __shared__ f16 Bs[64][40];
  int bx = blockIdx.x, by = blockIdx.y;
  int tid = threadIdx.x;
  int w = tid >> 6, l = tid & 63;
  int row0 = bx * 64 + w * 16;
  int col0 = by * 64;
  int arow = row0 + (l & 15);
  int kg = (l >> 4) * 8;
  f32x4 acc[4];
  for (int nt = 0; nt < 4; nt++) {
    float bv = Wb[col0 + nt * 16 + (l & 15)];
    f32x4 t = {bv, bv, bv, bv};
    acc[nt] = t;
  }
  for (int kb = 0; kb < 1024; kb += 32) {
    __syncthreads();
    for (int idx = tid; idx < 2048; idx += 256) {
      int n = idx & 63, kl = idx >> 6;
      Bs[n][kl] = (f16)Wk[(size_t)(kb + kl) * NH + col0 + n];
    }
    __syncthreads();
    f16x8 av = *(const f16x8*)(A2 + (size_t)arow * 1024 + kb + kg);
    for (int nt = 0; nt < 4; nt++) {
      f16x8 bv = *(const f16x8*)(&Bs[nt * 16 + (l & 15)][kg]);
      acc[nt] = __builtin_amdgcn_mfma_f32_16x16x32_f16(av, bv, acc[nt], 0, 0, 0);
    }
  }
  for (int nt = 0; nt < 4; nt++)
    for (int r = 0; r < 4; r++) {
      int grow = row0 + (l >> 4) * 4 + r;
      if (grow < 16416)
        Out[(size_t)grow * NH + col0 + nt * 16 + (l & 15)] = acc[nt][r];
    }
}

extern "C" void kernel_launch(void* const* d_in, const int* in_sizes, int n_in,
                              void* d_out, int out_size, void* d_ws, size_t ws_size,
                              hipStream_t stream) {
  (void)in_sizes; (void)n_in; (void)out_size;
  const int*   seqs = (const int*)d_in[0];
  const int*   lens = (const int*)d_in[1];
  const float* emb  = (const float*)d_in[2];
  const float* k_f  = (const float*)d_in[3];
  const float* rk_f = (const float*)d_in[4];
  const float* b_f  = (const float*)d_in[5];
  const float* k_b  = (const float*)d_in[6];
  const float* rk_b = (const float*)d_in[7];
  const float* b_b  = (const float*)d_in[8];
  const float* Wk   = (const float*)d_in[9];
  const float* Wb   = (const float*)d_in[10];
  float* out = (float*)d_out;
  char* ws = (char*)d_ws;
  f16* A2     = (f16*)(ws + 0);
  f16* Ahi    = (f16*)(ws + 0);            // aliases A2; dead before A2 written
  f16* Alo    = (f16*)(ws + 16777216);
  f16* xs2_f  = (f16*)(ws + XS2F_OFF);
  f16* xs2_b  = (f16*)(ws + XS2B_OFF);

  // ring depth: 512 (fully write-once) if ws fits, else 64 (reuse distance still
  // far beyond L2 retention given ~130KB/step/XCD of fresh traffic)
  int ring = 512;
  size_t need512 = (size_t)HB_OFF + 2ull * 512 * 32768 + (size_t)FLAGS_U32 * 4;
  if (ws_size < need512) ring = 64;
  u16* hb_f = (u16*)(ws + HB_OFF);
  u16* hb_b = hb_f + (size_t)ring * PLANE_E;
  u32* flags = (u32*)(ws + HB_OFF + 2ull * ring * 32768);
  int ring_mask = ring - 1;

  hipLaunchKernelGGL(k_embed, dim3(16384), dim3(128), 0, stream, seqs, emb, Ahi, Alo, A2, flags);
  hipLaunchKernelGGL(k_gemm_in, dim3(256, 24), dim3(256), 0, stream, Ahi, Alo, k_f, b_f, xs2_f);
  hipLaunchKernelGGL(k_gemm_in, dim3(256, 24), dim3(256), 0, stream, Ahi, Alo, k_b, b_b, xs2_b);
  hipLaunchKernelGGL(k_recur, dim3(64), dim3(128), 0, stream,
                     xs2_f, xs2_b, rk_f, rk_b, b_f, b_b, lens, hb_f, hb_b, A2, flags, ring_mask);
  hipLaunchKernelGGL(k_gemm_out, dim3(257, 8), dim3(256), 0, stream, A2, Wk, Wb, out);
}